// Round 1
// baseline (169.428 us; speedup 1.0000x reference)
//
#include <hip/hip_runtime.h>

#define NN 160      // nodes = STATE + ACT
#define BB 128      // batch
#define HH 256      // hidden
#define EE 5120     // edges
#define ST 128      // state dim
#define AC 32       // action dim
#define ITILE 16    // i-rows per block

// ---------- graph structure (batch-independent) ----------

__global__ void k_zero(int* cnt, int* degi) {
    int i = blockIdx.x * 256 + threadIdx.x;
    if (i < NN * NN) cnt[i] = 0;
    if (i < NN) degi[i] = 0;
}

__global__ void k_count(const int* ei, int* cnt, int* degi) {
    int e = blockIdx.x * 256 + threadIdx.x;
    if (e < EE) {
        int s = ei[e];
        int d = ei[EE + e];
        atomicAdd(&cnt[d * NN + s], 1);
        atomicAdd(&degi[d], 1);
    }
}

// M[i,j] = cnt[i,j]/max(deg[i],1);  A[i,j] = (cnt>0 || i==j) ? 1 : 0
__global__ void k_ma(const int* cnt, const int* degi, float* M, float* A) {
    int idx = blockIdx.x * 256 + threadIdx.x;
    if (idx >= NN * NN) return;
    int i = idx / NN, j = idx % NN;
    int dg = degi[i]; if (dg < 1) dg = 1;
    int c = cnt[idx];
    M[idx] = (float)c / (float)dg;
    A[idx] = (c > 0 || i == j) ? 1.0f : 0.0f;
}

// P = M @ A  (160x160x160, one-time)
__global__ void k_p(const float* M, const float* A, float* P) {
    __shared__ float Mi[NN];
    int i = blockIdx.x;
    int t = threadIdx.x;
    if (t < NN) Mi[t] = M[i * NN + t];
    __syncthreads();
    if (t < NN) {
        float acc = 0.f;
        for (int k = 0; k < NN; k++) acc += Mi[k] * A[k * NN + t];
        P[i * NN + t] = acc;
    }
}

// ---------- batched layers ----------

// h1[b,i,h] = relu( sum_j P[i,j]*x[b,j]*W1[j,h] + b1[h] )
__global__ void k_layer1(const float* __restrict__ P,
                         const float* __restrict__ state,
                         const float* __restrict__ action,
                         const float* __restrict__ W1,
                         const float* __restrict__ b1,
                         float* __restrict__ h1) {
    int b = blockIdx.y;
    int i0 = blockIdx.x * ITILE;
    int h = threadIdx.x;  // 256
    __shared__ float xb[NN];
    __shared__ float px[ITILE][NN];
    if (h < NN) xb[h] = (h < ST) ? state[b * ST + h] : action[b * AC + (h - ST)];
    __syncthreads();
    for (int idx = h; idx < ITILE * NN; idx += 256) {
        int ii = idx / NN, j = idx % NN;
        px[ii][j] = P[(i0 + ii) * NN + j] * xb[j];
    }
    __syncthreads();
    float acc[ITILE];
#pragma unroll
    for (int ii = 0; ii < ITILE; ii++) acc[ii] = 0.f;
    for (int j = 0; j < NN; j++) {
        float w = W1[j * HH + h];
#pragma unroll
        for (int ii = 0; ii < ITILE; ii++) acc[ii] += px[ii][j] * w;
    }
    float bias = b1[h];
#pragma unroll
    for (int ii = 0; ii < ITILE; ii++) {
        float v = acc[ii] + bias;
        h1[((size_t)b * NN + i0 + ii) * HH + h] = v > 0.f ? v : 0.f;
    }
}

// t[b,i,h] = sum_k M[i,k]*h1[b,k,h]
__global__ void k_agg2(const float* __restrict__ M,
                       const float* __restrict__ h1,
                       float* __restrict__ t) {
    int b = blockIdx.y;
    int i0 = blockIdx.x * ITILE;
    int h = threadIdx.x;
    __shared__ float Mi[ITILE][NN];
    for (int idx = h; idx < ITILE * NN; idx += 256) {
        Mi[idx / NN][idx % NN] = M[(i0 + idx / NN) * NN + (idx % NN)];
    }
    __syncthreads();
    float acc[ITILE];
#pragma unroll
    for (int ii = 0; ii < ITILE; ii++) acc[ii] = 0.f;
    const float* hb = h1 + (size_t)b * NN * HH + h;
    for (int k = 0; k < NN; k++) {
        float v = hb[(size_t)k * HH];
#pragma unroll
        for (int ii = 0; ii < ITILE; ii++) acc[ii] += Mi[ii][k] * v;
    }
#pragma unroll
    for (int ii = 0; ii < ITILE; ii++)
        t[((size_t)b * NN + i0 + ii) * HH + h] = acc[ii];
}

// h2[b,i,h] = relu( sum_k t[b,i,k]*W2[k,h] + b2[h] )
__global__ void k_mm2(const float* __restrict__ t,
                      const float* __restrict__ W2,
                      const float* __restrict__ b2,
                      float* __restrict__ h2) {
    int b = blockIdx.y;
    int i0 = blockIdx.x * ITILE;
    int h = threadIdx.x;
    __shared__ float tt[ITILE][HH];
#pragma unroll
    for (int ii = 0; ii < ITILE; ii++)
        tt[ii][h] = t[((size_t)b * NN + i0 + ii) * HH + h];
    __syncthreads();
    float acc[ITILE];
#pragma unroll
    for (int ii = 0; ii < ITILE; ii++) acc[ii] = 0.f;
    for (int k = 0; k < HH; k++) {
        float w = W2[k * HH + h];
#pragma unroll
        for (int ii = 0; ii < ITILE; ii++) acc[ii] += tt[ii][k] * w;
    }
    float bias = b2[h];
#pragma unroll
    for (int ii = 0; ii < ITILE; ii++) {
        float v = acc[ii] + bias;
        h2[((size_t)b * NN + i0 + ii) * HH + h] = v > 0.f ? v : 0.f;
    }
}

// pooled[b,h] = mean_i h2[b,i,h];  out[b,s] = pooled[b]·Wo[:,s] + bo[s] + state[b,s]
__global__ void k_pool(const float* __restrict__ h2,
                       const float* __restrict__ Wo,
                       const float* __restrict__ bo,
                       const float* __restrict__ state,
                       float* __restrict__ out) {
    int b = blockIdx.x;
    int h = threadIdx.x;  // 256
    __shared__ float pooled[HH];
    const float* hb = h2 + (size_t)b * NN * HH;
    float s = 0.f;
    for (int i = 0; i < NN; i++) s += hb[(size_t)i * HH + h];
    pooled[h] = s * (1.0f / NN);
    __syncthreads();
    if (h < ST) {
        float acc = bo[h];
        for (int k = 0; k < HH; k++) acc += pooled[k] * Wo[k * ST + h];
        out[b * ST + h] = acc + state[b * ST + h];
    }
}

extern "C" void kernel_launch(void* const* d_in, const int* in_sizes, int n_in,
                              void* d_out, int out_size, void* d_ws, size_t ws_size,
                              hipStream_t stream) {
    const float* state  = (const float*)d_in[0];
    const float* action = (const float*)d_in[1];
    const int*   ei     = (const int*)d_in[2];
    const float* W1     = (const float*)d_in[3];
    const float* b1     = (const float*)d_in[4];
    const float* W2     = (const float*)d_in[5];
    const float* b2     = (const float*)d_in[6];
    const float* Wo     = (const float*)d_in[7];
    const float* bo     = (const float*)d_in[8];
    float* out = (float*)d_out;

    char* ws = (char*)d_ws;
    int* cnt   = (int*)ws;                         // 160*160 ints
    int* degi  = cnt + NN * NN;                    // 160 ints
    float* M   = (float*)(degi + NN);              // 160*160 f32
    float* A   = M + NN * NN;                      // 160*160 f32
    float* P   = A + NN * NN;                      // 160*160 f32
    float* h1  = P + NN * NN;                      // 128*160*256 f32 (21 MB)
    float* t   = h1 + (size_t)BB * NN * HH;        // 128*160*256 f32 (21 MB)
    float* h2  = h1;                               // alias: h1 dead after agg2

    k_zero<<<(NN * NN + 255) / 256, 256, 0, stream>>>(cnt, degi);
    k_count<<<(EE + 255) / 256, 256, 0, stream>>>(ei, cnt, degi);
    k_ma<<<(NN * NN + 255) / 256, 256, 0, stream>>>(cnt, degi, M, A);
    k_p<<<NN, 256, 0, stream>>>(M, A, P);

    dim3 grid(NN / ITILE, BB);  // (10, 128)
    k_layer1<<<grid, 256, 0, stream>>>(P, state, action, W1, b1, h1);
    k_agg2<<<grid, 256, 0, stream>>>(M, h1, t);
    k_mm2<<<grid, 256, 0, stream>>>(t, W2, b2, h2);
    k_pool<<<BB, 256, 0, stream>>>(h2, Wo, bo, state, out);
}

// Round 2
// 84.758 us; speedup vs baseline: 1.9990x; 1.9990x over previous
//
#include <hip/hip_runtime.h>

#define NN 160      // nodes
#define BB 128      // batch
#define HH 256      // hidden
#define EE 5120     // edges
#define ST 128      // state dim
#define AC 32       // action dim

typedef __attribute__((ext_vector_type(8))) short short8;
typedef __attribute__((ext_vector_type(4))) float f32x4;

__device__ inline unsigned short f2b(float f) {
    unsigned u = __builtin_bit_cast(unsigned, f);
    unsigned r = (u + 0x7FFFu + ((u >> 16) & 1u)) >> 16;
    return (unsigned short)r;
}
__device__ inline float b2f(unsigned short h) {
    return __builtin_bit_cast(float, (unsigned)h << 16);
}

// ---------- graph structure (batch-independent, tiny) ----------

__global__ void k_zero(int* cnt, int* degi) {
    int i = blockIdx.x * 256 + threadIdx.x;
    if (i < NN * NN) cnt[i] = 0;
    if (i < NN) degi[i] = 0;
}

__global__ void k_count(const int* ei, int* cnt, int* degi) {
    int e = blockIdx.x * 256 + threadIdx.x;
    if (e < EE) {
        int s = ei[e];
        int d = ei[EE + e];
        atomicAdd(&cnt[d * NN + s], 1);
        atomicAdd(&degi[d], 1);
    }
}

// M=cnt/deg (fp32 + bf16), A = adjacency(+self loop)
__global__ void k_ma(const int* cnt, const int* degi, float* M, float* A,
                     unsigned short* Mb) {
    int idx = blockIdx.x * 256 + threadIdx.x;
    if (idx >= NN * NN) return;
    int i = idx / NN, j = idx % NN;
    int dg = degi[i]; if (dg < 1) dg = 1;
    int c = cnt[idx];
    float m = (float)c / (float)dg;
    M[idx] = m;
    Mb[idx] = f2b(m);
    A[idx] = (c > 0 || i == j) ? 1.0f : 0.0f;
}

// P = M @ A  (fp32, one-time)
__global__ void k_p(const float* M, const float* A, float* P) {
    __shared__ float Mi[NN];
    int i = blockIdx.x;
    int t = threadIdx.x;
    if (t < NN) Mi[t] = M[i * NN + t];
    __syncthreads();
    if (t < NN) {
        float acc = 0.f;
        for (int k = 0; k < NN; k++) acc += Mi[k] * A[k * NN + t];
        P[i * NN + t] = acc;
    }
}

// W1t[n][k] = W1[k][n] (bf16), W2t[n][k] = W2[k][n] (bf16)
__global__ void k_wt(const float* W1, const float* W2,
                     unsigned short* W1t, unsigned short* W2t) {
    int idx = blockIdx.x * 256 + threadIdx.x;
    if (idx < NN * HH) {
        int n = idx / NN, k = idx % NN;
        W1t[idx] = f2b(W1[k * HH + n]);
    } else if (idx < NN * HH + HH * HH) {
        int j = idx - NN * HH;
        int n = j >> 8, k = j & 255;
        W2t[j] = f2b(W2[k * HH + n]);
    }
}

// Ybf[(b*NN+i)][j] = bf16(P[i][j] * x[b][j])
__global__ void k_y(const float* __restrict__ P,
                    const float* __restrict__ state,
                    const float* __restrict__ action,
                    unsigned short* __restrict__ Ybf) {
    int idx = blockIdx.x * 256 + threadIdx.x;
    if (idx >= BB * NN * NN) return;
    int b = idx / (NN * NN);
    int rem = idx - b * (NN * NN);
    int j = rem % NN;
    float x = (j < ST) ? state[b * ST + j] : action[b * AC + (j - ST)];
    Ybf[idx] = f2b(P[rem] * x);
}

// ---------- generic bf16 MFMA GEMM: C[m][n] = sum_k A[m][k]*Bt[n][k] ----------
// BIAS: 0 none, 1 per-row, 2 per-col.  4 waves (2x2), BK=32.

template<int K, int BM, int BN, int BIAS, int RELU>
__global__ __launch_bounds__(256)
void gemm_bt(const unsigned short* __restrict__ A,
             const unsigned short* __restrict__ Bt,
             const float* __restrict__ bias,
             unsigned short* __restrict__ C,
             int ldc, long strA, long strB, long strC)
{
    constexpr int LDSS = 40;                 // padded K-stride (bank spread)
    constexpr int WM = BM / 2, WN = BN / 2;
    constexpr int FM = WM / 16, FN = WN / 16;
    __shared__ __align__(16) unsigned short sA[BM][LDSS];
    __shared__ __align__(16) unsigned short sB[BN][LDSS];

    const int b = blockIdx.z;
    const unsigned short* Ab  = A  + (size_t)b * strA;
    const unsigned short* Btb = Bt + (size_t)b * strB;
    unsigned short* Cb = C + (size_t)b * strC;
    const int m0 = blockIdx.x * BM, n0 = blockIdx.y * BN;
    const int tid = threadIdx.x, lane = tid & 63, w = tid >> 6;
    const int wr = w >> 1, wc = w & 1;
    const int rl = lane & 15, kq = lane >> 4;

    f32x4 acc[FM][FN];
    for (int i = 0; i < FM; i++)
        for (int j = 0; j < FN; j++)
            acc[i][j] = f32x4{0.f, 0.f, 0.f, 0.f};

    for (int k0 = 0; k0 < K; k0 += 32) {
        for (int idx = tid; idx < (BM + BN) * 4; idx += 256) {
            int r = idx >> 2, c = (idx & 3) * 8;
            if (r < BM) {
                *(short8*)&sA[r][c] =
                    *(const short8*)&Ab[(size_t)(m0 + r) * K + k0 + c];
            } else {
                int rb = r - BM;
                *(short8*)&sB[rb][c] =
                    *(const short8*)&Btb[(size_t)(n0 + rb) * K + k0 + c];
            }
        }
        __syncthreads();
        short8 af[FM], bf[FN];
#pragma unroll
        for (int i = 0; i < FM; i++)
            af[i] = *(const short8*)&sA[wr * WM + i * 16 + rl][kq * 8];
#pragma unroll
        for (int j = 0; j < FN; j++)
            bf[j] = *(const short8*)&sB[wc * WN + j * 16 + rl][kq * 8];
#pragma unroll
        for (int i = 0; i < FM; i++)
#pragma unroll
            for (int j = 0; j < FN; j++)
                acc[i][j] = __builtin_amdgcn_mfma_f32_16x16x32_bf16(
                    af[i], bf[j], acc[i][j], 0, 0, 0);
        __syncthreads();
    }

    // epilogue: C/D layout col=lane&15, row=(lane>>4)*4+reg  [m89/m91]
#pragma unroll
    for (int i = 0; i < FM; i++)
#pragma unroll
        for (int j = 0; j < FN; j++) {
            int col  = n0 + wc * WN + j * 16 + rl;
            int rowb = m0 + wr * WM + i * 16 + kq * 4;
            float bc = (BIAS == 2) ? bias[col] : 0.f;
#pragma unroll
            for (int r = 0; r < 4; r++) {
                int row = rowb + r;
                float v = acc[i][j][r];
                if (BIAS == 1) v += bias[row];
                if (BIAS == 2) v += bc;
                if (RELU) v = v > 0.f ? v : 0.f;
                Cb[(size_t)row * ldc + col] = f2b(v);
            }
        }
}

// ---------- pool + output head ----------
// pooled[b][h] = mean_i h2[b][i][h];  out = pooled@Wo + bo + state
__global__ void k_pool(const unsigned short* __restrict__ h2,
                       const float* __restrict__ Wo,
                       const float* __restrict__ bo,
                       const float* __restrict__ state,
                       float* __restrict__ out) {
    int b = blockIdx.x;
    int h = threadIdx.x;  // 256
    __shared__ float pooled[HH];
    const unsigned short* hb = h2 + (size_t)b * NN * HH;
    float s = 0.f;
    for (int i = 0; i < NN; i++) s += b2f(hb[(size_t)i * HH + h]);
    pooled[h] = s * (1.0f / NN);
    __syncthreads();
    if (h < ST) {
        float acc = bo[h];
        for (int k = 0; k < HH; k++) acc += pooled[k] * Wo[k * ST + h];
        out[b * ST + h] = acc + state[b * ST + h];
    }
}

extern "C" void kernel_launch(void* const* d_in, const int* in_sizes, int n_in,
                              void* d_out, int out_size, void* d_ws, size_t ws_size,
                              hipStream_t stream) {
    const float* state  = (const float*)d_in[0];
    const float* action = (const float*)d_in[1];
    const int*   ei     = (const int*)d_in[2];
    const float* W1     = (const float*)d_in[3];
    const float* b1     = (const float*)d_in[4];
    const float* W2     = (const float*)d_in[5];
    const float* b2     = (const float*)d_in[6];
    const float* Wo     = (const float*)d_in[7];
    const float* bo     = (const float*)d_in[8];
    float* out = (float*)d_out;

    char* ws = (char*)d_ws;
    size_t off = 0;
    auto alloc = [&](size_t bytes) {
        void* p = ws + off;
        off += (bytes + 255) & ~(size_t)255;
        return p;
    };
    int*   cnt  = (int*)alloc(NN * NN * 4);
    int*   degi = (int*)alloc(NN * 4);
    float* M    = (float*)alloc(NN * NN * 4);
    float* A    = (float*)alloc(NN * NN * 4);
    float* P    = (float*)alloc(NN * NN * 4);
    unsigned short* Mb  = (unsigned short*)alloc(NN * NN * 2);
    unsigned short* W1t = (unsigned short*)alloc((size_t)HH * NN * 2);
    unsigned short* W2t = (unsigned short*)alloc((size_t)HH * HH * 2);
    unsigned short* Ybf = (unsigned short*)alloc((size_t)BB * NN * NN * 2);
    unsigned short* h1t = (unsigned short*)alloc((size_t)BB * HH * NN * 2);
    unsigned short* t   = (unsigned short*)alloc((size_t)BB * NN * HH * 2);
    unsigned short* h2  = h1t;  // h1t dead after agg2

    k_zero<<<(NN * NN + 255) / 256, 256, 0, stream>>>(cnt, degi);
    k_count<<<(EE + 255) / 256, 256, 0, stream>>>(ei, cnt, degi);
    k_ma<<<(NN * NN + 255) / 256, 256, 0, stream>>>(cnt, degi, M, A, Mb);
    k_p<<<NN, 256, 0, stream>>>(M, A, P);
    k_wt<<<(NN * HH + HH * HH + 255) / 256, 256, 0, stream>>>(W1, W2, W1t, W2t);
    k_y<<<(BB * NN * NN + 255) / 256, 256, 0, stream>>>(P, state, action, Ybf);

    // layer1 (transposed): h1t[b][h][i] = relu(sum_j W1t[h][j] * Ybf[b][i][j] + b1[h])
    {
        dim3 g(HH / 64, NN / 32, BB);
        gemm_bt<NN, 64, 32, 1, 1><<<g, 256, 0, stream>>>(
            W1t, Ybf, b1, h1t, NN, 0, (long)NN * NN, (long)HH * NN);
    }
    // agg2: t[b][i][h] = sum_k Mb[i][k] * h1t[b][h][k]
    {
        dim3 g(NN / 32, HH / 64, BB);
        gemm_bt<NN, 32, 64, 0, 0><<<g, 256, 0, stream>>>(
            Mb, h1t, nullptr, t, HH, 0, (long)HH * NN, (long)NN * HH);
    }
    // mm2: h2[(b,i)][h] = relu(sum_k t[(b,i)][k] * W2t[h][k] + b2[h])
    {
        dim3 g(BB * NN / 64, HH / 64, 1);
        gemm_bt<HH, 64, 64, 2, 1><<<g, 256, 0, stream>>>(
            t, W2t, b2, h2, HH, 0, 0, 0);
    }
    k_pool<<<BB, 256, 0, stream>>>(h2, Wo, bo, state, out);
}

// Round 3
// 72.849 us; speedup vs baseline: 2.3258x; 1.1635x over previous
//
#include <hip/hip_runtime.h>

#define NN 160      // nodes
#define BB 128      // batch
#define HH 256      // hidden
#define EE 5120     // edges
#define ST 128      // state dim
#define AC 32       // action dim
#define HALF 128    // HH/2

typedef __attribute__((ext_vector_type(8))) short short8;
typedef __attribute__((ext_vector_type(4))) float f32x4;

__device__ inline unsigned short f2b(float f) {
    unsigned u = __builtin_bit_cast(unsigned, f);
    unsigned r = (u + 0x7FFFu + ((u >> 16) & 1u)) >> 16;
    return (unsigned short)r;
}

// ---------- K1: graph structure in LDS + zero pooled (1 block) ----------
__global__ __launch_bounds__(1024)
void k_graph(const int* __restrict__ ei, float* __restrict__ M,
             float* __restrict__ A, unsigned short* __restrict__ Mb,
             float* __restrict__ pooled) {
    __shared__ int cnt[NN * NN];   // 102.4 KB
    __shared__ int deg[NN];
    int tid = threadIdx.x;
    for (int i = tid; i < NN * NN; i += 1024) cnt[i] = 0;
    if (tid < NN) deg[tid] = 0;
    for (int i = tid; i < BB * HH; i += 1024) pooled[i] = 0.f;
    __syncthreads();
    for (int e = tid; e < EE; e += 1024) {
        int s = ei[e], d = ei[EE + e];
        atomicAdd(&cnt[d * NN + s], 1);
        atomicAdd(&deg[d], 1);
    }
    __syncthreads();
    for (int idx = tid; idx < NN * NN; idx += 1024) {
        int i = idx / NN, j = idx - (idx / NN) * NN;
        int dg = deg[i]; if (dg < 1) dg = 1;
        int c = cnt[idx];
        float m = (float)c / (float)dg;
        M[idx] = m;
        Mb[idx] = f2b(m);
        A[idx] = (c > 0 || i == j) ? 1.0f : 0.0f;
    }
}

// ---------- K2: P = M@A (fp32) + W1t/W2t transpose to bf16 ----------
__global__ __launch_bounds__(256)
void k_pwt(const float* __restrict__ M, const float* __restrict__ A,
           const float* __restrict__ W1, const float* __restrict__ W2,
           float* __restrict__ P, unsigned short* __restrict__ W1t,
           unsigned short* __restrict__ W2t) {
    int bx = blockIdx.x, t = threadIdx.x;
    if (bx < NN) {
        __shared__ float Mi[NN];
        if (t < NN) Mi[t] = M[bx * NN + t];
        __syncthreads();
        if (t < NN) {
            float acc = 0.f;
            for (int k = 0; k < NN; k++) acc += Mi[k] * A[k * NN + t];
            P[bx * NN + t] = acc;
        }
    } else if (bx < NN + 160) {                   // W1t: 256x160 = 40960
        int idx = (bx - NN) * 256 + t;
        int n = idx / NN, k = idx - n * NN;
        W1t[idx] = f2b(W1[k * HH + n]);
    } else {                                      // W2t: 256x256 = 65536
        int idx = (bx - NN - 160) * 256 + t;
        int n = idx >> 8, k = idx & 255;
        W2t[idx] = f2b(W2[k * HH + n]);
    }
}

// ---------- K3: fused layer1 + agg2 per (h-half, batch) ----------
// GEMM1: h1[hh][i] = relu( sum_j W1t[ho+hh][j] * (P[i][j]*x[b][j]) + b1[ho+hh] )
// GEMM2: t[b][i][ho+hh] = sum_k Mb[i][k] * h1[hh][k]
__global__ __launch_bounds__(256)
void k_l1agg(const float* __restrict__ P, const float* __restrict__ state,
             const float* __restrict__ action,
             const unsigned short* __restrict__ W1t,
             const float* __restrict__ b1,
             const unsigned short* __restrict__ Mb,
             unsigned short* __restrict__ t_out)
{
    constexpr int KS = 40;    // staging K-stride (shorts)
    constexpr int H1S = 168;  // h1 row stride (shorts), 336 B (16B-mult)
    __shared__ __align__(16) float xb[NN];
    __shared__ __align__(16) unsigned short h1[HALF][H1S];          // 43 KB
    __shared__ __align__(16) unsigned short stg[(NN + HALF) * KS];  // 23 KB
    unsigned short* sY = stg;            // [NN][KS]   (GEMM1 Bt)
    unsigned short* sW = stg + NN * KS;  // [HALF][KS] (GEMM1 A)
    unsigned short* sM = stg;            // [NN][KS]   (GEMM2 A, reuse)

    const int b = blockIdx.y, ho = blockIdx.x * HALF;
    const int tid = threadIdx.x, lane = tid & 63, w = tid >> 6;
    const int wr = w >> 1, wc = w & 1;
    const int rl = lane & 15, kq = lane >> 4;

    if (tid < NN) xb[tid] = (tid < ST) ? state[b * ST + tid]
                                       : action[b * AC + (tid - ST)];
    __syncthreads();

    // ---- GEMM1: M=128 (hh), N=160 (i), K=160 (j). waves 2x2: WM=64,WN=80
    {
        f32x4 acc[4][5];
#pragma unroll
        for (int f = 0; f < 4; f++)
#pragma unroll
            for (int j = 0; j < 5; j++) acc[f][j] = f32x4{0.f, 0.f, 0.f, 0.f};

        for (int k0 = 0; k0 < NN; k0 += 32) {
            for (int idx = tid; idx < 512 + 640; idx += 256) {
                if (idx < 512) {            // A: W1t half rows
                    int r = idx >> 2, c = (idx & 3) * 8;
                    *(short8*)&sW[r * KS + c] =
                        *(const short8*)&W1t[(size_t)(ho + r) * NN + k0 + c];
                } else {                    // Bt: Y = bf16(P*x) on the fly
                    int q = idx - 512;
                    int r = q >> 2, c = (q & 3) * 8;
                    const f32x4* p4 = (const f32x4*)&P[r * NN + k0 + c];
                    f32x4 p0 = p4[0], p1 = p4[1];
                    short8 y;
#pragma unroll
                    for (int u = 0; u < 4; u++) {
                        y[u]     = (short)f2b(p0[u] * xb[k0 + c + u]);
                        y[u + 4] = (short)f2b(p1[u] * xb[k0 + c + 4 + u]);
                    }
                    *(short8*)&sY[r * KS + c] = y;
                }
            }
            __syncthreads();
            short8 af[4], bf[5];
#pragma unroll
            for (int f = 0; f < 4; f++)
                af[f] = *(const short8*)&sW[(wr * 64 + f * 16 + rl) * KS + kq * 8];
#pragma unroll
            for (int j = 0; j < 5; j++)
                bf[j] = *(const short8*)&sY[(wc * 80 + j * 16 + rl) * KS + kq * 8];
#pragma unroll
            for (int f = 0; f < 4; f++)
#pragma unroll
                for (int j = 0; j < 5; j++)
                    acc[f][j] = __builtin_amdgcn_mfma_f32_16x16x32_bf16(
                        af[f], bf[j], acc[f][j], 0, 0, 0);
            __syncthreads();
        }
        // epilogue -> LDS h1 (bias + relu), C/D layout col=rl, row=kq*4+r
#pragma unroll
        for (int f = 0; f < 4; f++) {
            int rowb = wr * 64 + f * 16 + kq * 4;
#pragma unroll
            for (int j = 0; j < 5; j++) {
                int col = wc * 80 + j * 16 + rl;
#pragma unroll
                for (int r = 0; r < 4; r++) {
                    int row = rowb + r;
                    float v = acc[f][j][r] + b1[ho + row];
                    h1[row][col] = f2b(v > 0.f ? v : 0.f);
                }
            }
        }
    }
    __syncthreads();

    // ---- GEMM2: M=160 (i), N=128 (hh), K=160 (k). waves 2x2: WM=80,WN=64
    {
        f32x4 acc[5][4];
#pragma unroll
        for (int f = 0; f < 5; f++)
#pragma unroll
            for (int j = 0; j < 4; j++) acc[f][j] = f32x4{0.f, 0.f, 0.f, 0.f};

        for (int k0 = 0; k0 < NN; k0 += 32) {
            for (int idx = tid; idx < 640; idx += 256) {
                int r = idx >> 2, c = (idx & 3) * 8;
                *(short8*)&sM[r * KS + c] =
                    *(const short8*)&Mb[(size_t)r * NN + k0 + c];
            }
            __syncthreads();
            short8 af[5], bf[4];
#pragma unroll
            for (int f = 0; f < 5; f++)
                af[f] = *(const short8*)&sM[(wr * 80 + f * 16 + rl) * KS + kq * 8];
#pragma unroll
            for (int j = 0; j < 4; j++)
                bf[j] = *(const short8*)&h1[wc * 64 + j * 16 + rl][k0 + kq * 8];
#pragma unroll
            for (int f = 0; f < 5; f++)
#pragma unroll
                for (int j = 0; j < 4; j++)
                    acc[f][j] = __builtin_amdgcn_mfma_f32_16x16x32_bf16(
                        af[f], bf[j], acc[f][j], 0, 0, 0);
            __syncthreads();
        }
        // epilogue -> global t
#pragma unroll
        for (int f = 0; f < 5; f++) {
            int rowb = wr * 80 + f * 16 + kq * 4;
#pragma unroll
            for (int j = 0; j < 4; j++) {
                int col = ho + wc * 64 + j * 16 + rl;
#pragma unroll
                for (int r = 0; r < 4; r++) {
                    int row = rowb + r;
                    t_out[((size_t)b * NN + row) * HH + col] = f2b(acc[f][j][r]);
                }
            }
        }
    }
}

// ---------- K4: mm2 + pooled accumulation ----------
// h2[b][i][h] = relu(sum_k t[b][i][k]*W2t[h][k] + b2[h]); pooled[b][h] += sum_i h2
__global__ __launch_bounds__(256)
void k_mm2pool(const unsigned short* __restrict__ t_in,
               const unsigned short* __restrict__ W2t,
               const float* __restrict__ b2,
               float* __restrict__ pooled)
{
    constexpr int KS = 40;
    __shared__ __align__(16) unsigned short sT[32 * KS];   // 2.5 KB
    __shared__ __align__(16) unsigned short sW[HH * KS];   // 20 KB
    __shared__ float pp[HH];
    const int b = blockIdx.y, i0 = blockIdx.x * 32;
    const int tid = threadIdx.x, lane = tid & 63, w = tid >> 6;
    const int wr = w >> 1, wc = w & 1;
    const int rl = lane & 15, kq = lane >> 4;

    pp[tid] = 0.f;

    f32x4 acc[8];
#pragma unroll
    for (int j = 0; j < 8; j++) acc[j] = f32x4{0.f, 0.f, 0.f, 0.f};

    for (int k0 = 0; k0 < HH; k0 += 32) {
        for (int idx = tid; idx < 128 + 1024; idx += 256) {
            if (idx < 128) {
                int r = idx >> 2, c = (idx & 3) * 8;
                *(short8*)&sT[r * KS + c] =
                    *(const short8*)&t_in[((size_t)b * NN + i0 + r) * HH + k0 + c];
            } else {
                int q = idx - 128;
                int r = q >> 2, c = (q & 3) * 8;
                *(short8*)&sW[r * KS + c] =
                    *(const short8*)&W2t[(size_t)r * HH + k0 + c];
            }
        }
        __syncthreads();
        short8 af = *(const short8*)&sT[(wr * 16 + rl) * KS + kq * 8];
        short8 bf[8];
#pragma unroll
        for (int j = 0; j < 8; j++)
            bf[j] = *(const short8*)&sW[(wc * 128 + j * 16 + rl) * KS + kq * 8];
#pragma unroll
        for (int j = 0; j < 8; j++)
            acc[j] = __builtin_amdgcn_mfma_f32_16x16x32_bf16(af, bf[j], acc[j], 0, 0, 0);
        __syncthreads();
    }
    // epilogue: bias+relu, reduce over this lane's 4 rows, LDS-atomic per col
#pragma unroll
    for (int j = 0; j < 8; j++) {
        int col = wc * 128 + j * 16 + rl;
        float bias = b2[col];
        float s = 0.f;
#pragma unroll
        for (int r = 0; r < 4; r++) {
            float v = acc[j][r] + bias;
            s += v > 0.f ? v : 0.f;
        }
        atomicAdd(&pp[col], s);
    }
    __syncthreads();
    atomicAdd(&pooled[b * HH + tid], pp[tid]);
}

// ---------- K5: head: out = pooled/160 @ Wo + bo + state ----------
__global__ __launch_bounds__(128)
void k_head(const float* __restrict__ pooled, const float* __restrict__ Wo,
            const float* __restrict__ bo, const float* __restrict__ state,
            float* __restrict__ out) {
    __shared__ float pb[HH];
    int b = blockIdx.x, s = threadIdx.x;  // 128 threads
    pb[s]       = pooled[b * HH + s]       * (1.0f / NN);
    pb[s + 128] = pooled[b * HH + s + 128] * (1.0f / NN);
    __syncthreads();
    float acc = bo[s];
    for (int k = 0; k < HH; k++) acc += pb[k] * Wo[k * ST + s];
    out[b * ST + s] = acc + state[b * ST + s];
}

extern "C" void kernel_launch(void* const* d_in, const int* in_sizes, int n_in,
                              void* d_out, int out_size, void* d_ws, size_t ws_size,
                              hipStream_t stream) {
    const float* state  = (const float*)d_in[0];
    const float* action = (const float*)d_in[1];
    const int*   ei     = (const int*)d_in[2];
    const float* W1     = (const float*)d_in[3];
    const float* b1     = (const float*)d_in[4];
    const float* W2     = (const float*)d_in[5];
    const float* b2     = (const float*)d_in[6];
    const float* Wo     = (const float*)d_in[7];
    const float* bo     = (const float*)d_in[8];
    float* out = (float*)d_out;

    char* ws = (char*)d_ws;
    size_t off = 0;
    auto alloc = [&](size_t bytes) {
        void* p = ws + off;
        off += (bytes + 255) & ~(size_t)255;
        return p;
    };
    float* M    = (float*)alloc(NN * NN * 4);
    float* A    = (float*)alloc(NN * NN * 4);
    float* P    = (float*)alloc(NN * NN * 4);
    unsigned short* Mb  = (unsigned short*)alloc(NN * NN * 2);
    unsigned short* W1t = (unsigned short*)alloc((size_t)HH * NN * 2);
    unsigned short* W2t = (unsigned short*)alloc((size_t)HH * HH * 2);
    unsigned short* t   = (unsigned short*)alloc((size_t)BB * NN * HH * 2);
    float* pooled = (float*)alloc((size_t)BB * HH * 4);

    k_graph<<<1, 1024, 0, stream>>>(ei, M, A, Mb, pooled);
    k_pwt<<<576, 256, 0, stream>>>(M, A, W1, W2, P, W1t, W2t);
    {
        dim3 g(2, BB);   // (h-half, batch) = 256 blocks
        k_l1agg<<<g, 256, 0, stream>>>(P, state, action, W1t, b1, Mb, t);
    }
    {
        dim3 g(NN / 32, BB);  // (i-tile, batch) = 640 blocks
        k_mm2pool<<<g, 256, 0, stream>>>(t, W2t, b2, pooled);
    }
    k_head<<<BB, 128, 0, stream>>>(pooled, Wo, bo, state, out);
}

// Round 4
// 58.427 us; speedup vs baseline: 2.8998x; 1.2468x over previous
//
#include <hip/hip_runtime.h>

#define NN 160      // nodes
#define BB 128      // batch
#define HH 256      // hidden
#define EE 5120     // edges
#define ST 128      // state dim
#define AC 32       // action dim
#define HALF 128    // HH/2

typedef __attribute__((ext_vector_type(8))) short short8;
typedef __attribute__((ext_vector_type(4))) float f32x4;

__device__ inline unsigned short f2b(float f) {
    unsigned u = __builtin_bit_cast(unsigned, f);
    unsigned r = (u + 0x7FFFu + ((u >> 16) & 1u)) >> 16;
    return (unsigned short)r;
}

// ---------- K1: graph rows (block i owns row i; deg = row-sum) ----------
__global__ __launch_bounds__(256)
void k_rows(const int* __restrict__ ei, float* __restrict__ M,
            float* __restrict__ A, unsigned short* __restrict__ Mb) {
    __shared__ int crow[NN];
    __shared__ float degf;
    const int i = blockIdx.x, tid = threadIdx.x;
    if (tid < NN) crow[tid] = 0;
    __syncthreads();
    for (int e = tid; e < EE; e += 256) {
        int d = ei[EE + e];
        if (d == i) atomicAdd(&crow[ei[e]], 1);
    }
    __syncthreads();
    if (tid == 0) {
        int dg = 0;
        for (int j = 0; j < NN; j++) dg += crow[j];
        degf = (float)(dg < 1 ? 1 : dg);
    }
    __syncthreads();
    if (tid < NN) {
        int c = crow[tid];
        float m = (float)c / degf;
        M[i * NN + tid] = m;
        Mb[i * NN + tid] = f2b(m);
        A[i * NN + tid] = (c > 0 || i == tid) ? 1.0f : 0.0f;
    }
}

// ---------- K2: P = M@A (fp32) + W1t/W2t transpose to bf16 ----------
__global__ __launch_bounds__(256)
void k_pwt(const float* __restrict__ M, const float* __restrict__ A,
           const float* __restrict__ W1, const float* __restrict__ W2,
           float* __restrict__ P, unsigned short* __restrict__ W1t,
           unsigned short* __restrict__ W2t) {
    int bx = blockIdx.x, t = threadIdx.x;
    if (bx < NN) {
        __shared__ float Mi[NN];
        if (t < NN) Mi[t] = M[bx * NN + t];
        __syncthreads();
        if (t < NN) {
            float acc = 0.f;
            for (int k = 0; k < NN; k++) acc += Mi[k] * A[k * NN + t];
            P[bx * NN + t] = acc;
        }
    } else if (bx < NN + 160) {                   // W1t: 256x160 = 40960
        int idx = (bx - NN) * 256 + t;
        int n = idx / NN, k = idx - n * NN;
        W1t[idx] = f2b(W1[k * HH + n]);
    } else {                                      // W2t: 256x256 = 65536
        int idx = (bx - NN - 160) * 256 + t;
        int n = idx >> 8, k = idx & 255;
        W2t[idx] = f2b(W2[k * HH + n]);
    }
}

// ---------- K3: fused layer1 + agg2 per (h-half, batch) ----------
// GEMM1: h1[hh][i] = relu( sum_j W1t[ho+hh][j] * (P[i][j]*x[b][j]) + b1[ho+hh] )
// GEMM2: t[b][i][ho+hh] = sum_k Mb[i][k] * h1[hh][k]
__global__ __launch_bounds__(256)
void k_l1agg(const float* __restrict__ P, const float* __restrict__ state,
             const float* __restrict__ action,
             const unsigned short* __restrict__ W1t,
             const float* __restrict__ b1,
             const unsigned short* __restrict__ Mb,
             unsigned short* __restrict__ t_out)
{
    constexpr int KS = 40;    // staging K-stride (shorts)
    constexpr int H1S = 168;  // h1 row stride (shorts)
    __shared__ __align__(16) float xb[NN];
    __shared__ __align__(16) unsigned short h1[HALF][H1S];          // 43 KB
    __shared__ __align__(16) unsigned short stg[(NN + HALF) * KS];  // 23 KB
    unsigned short* sY = stg;            // [NN][KS]   (GEMM1 Bt)
    unsigned short* sW = stg + NN * KS;  // [HALF][KS] (GEMM1 A)
    unsigned short* sM = stg;            // [NN][KS]   (GEMM2 A, reuse)

    const int b = blockIdx.y, ho = blockIdx.x * HALF;
    const int tid = threadIdx.x, lane = tid & 63, w = tid >> 6;
    const int wr = w >> 1, wc = w & 1;
    const int rl = lane & 15, kq = lane >> 4;

    if (tid < NN) xb[tid] = (tid < ST) ? state[b * ST + tid]
                                       : action[b * AC + (tid - ST)];
    __syncthreads();

    // ---- GEMM1: M=128 (hh), N=160 (i), K=160 (j). waves 2x2: WM=64,WN=80
    {
        f32x4 acc[4][5];
#pragma unroll
        for (int f = 0; f < 4; f++)
#pragma unroll
            for (int j = 0; j < 5; j++) acc[f][j] = f32x4{0.f, 0.f, 0.f, 0.f};

        for (int k0 = 0; k0 < NN; k0 += 32) {
            for (int idx = tid; idx < 512 + 640; idx += 256) {
                if (idx < 512) {            // A: W1t half rows
                    int r = idx >> 2, c = (idx & 3) * 8;
                    *(short8*)&sW[r * KS + c] =
                        *(const short8*)&W1t[(size_t)(ho + r) * NN + k0 + c];
                } else {                    // Bt: Y = bf16(P*x) on the fly
                    int q = idx - 512;
                    int r = q >> 2, c = (q & 3) * 8;
                    const f32x4* p4 = (const f32x4*)&P[r * NN + k0 + c];
                    f32x4 p0 = p4[0], p1 = p4[1];
                    short8 y;
#pragma unroll
                    for (int u = 0; u < 4; u++) {
                        y[u]     = (short)f2b(p0[u] * xb[k0 + c + u]);
                        y[u + 4] = (short)f2b(p1[u] * xb[k0 + c + 4 + u]);
                    }
                    *(short8*)&sY[r * KS + c] = y;
                }
            }
            __syncthreads();
            short8 af[4], bf[5];
#pragma unroll
            for (int f = 0; f < 4; f++)
                af[f] = *(const short8*)&sW[(wr * 64 + f * 16 + rl) * KS + kq * 8];
#pragma unroll
            for (int j = 0; j < 5; j++)
                bf[j] = *(const short8*)&sY[(wc * 80 + j * 16 + rl) * KS + kq * 8];
#pragma unroll
            for (int f = 0; f < 4; f++)
#pragma unroll
                for (int j = 0; j < 5; j++)
                    acc[f][j] = __builtin_amdgcn_mfma_f32_16x16x32_bf16(
                        af[f], bf[j], acc[f][j], 0, 0, 0);
            __syncthreads();
        }
        // epilogue -> LDS h1 (bias + relu), C/D layout col=rl, row=kq*4+r
#pragma unroll
        for (int f = 0; f < 4; f++) {
            int rowb = wr * 64 + f * 16 + kq * 4;
#pragma unroll
            for (int j = 0; j < 5; j++) {
                int col = wc * 80 + j * 16 + rl;
#pragma unroll
                for (int r = 0; r < 4; r++) {
                    int row = rowb + r;
                    float v = acc[f][j][r] + b1[ho + row];
                    h1[row][col] = f2b(v > 0.f ? v : 0.f);
                }
            }
        }
    }
    __syncthreads();

    // ---- GEMM2: M=160 (i), N=128 (hh), K=160 (k). waves 2x2: WM=80,WN=64
    {
        f32x4 acc[5][4];
#pragma unroll
        for (int f = 0; f < 5; f++)
#pragma unroll
            for (int j = 0; j < 4; j++) acc[f][j] = f32x4{0.f, 0.f, 0.f, 0.f};

        for (int k0 = 0; k0 < NN; k0 += 32) {
            for (int idx = tid; idx < 640; idx += 256) {
                int r = idx >> 2, c = (idx & 3) * 8;
                *(short8*)&sM[r * KS + c] =
                    *(const short8*)&Mb[(size_t)r * NN + k0 + c];
            }
            __syncthreads();
            short8 af[5], bf[4];
#pragma unroll
            for (int f = 0; f < 5; f++)
                af[f] = *(const short8*)&sM[(wr * 80 + f * 16 + rl) * KS + kq * 8];
#pragma unroll
            for (int j = 0; j < 4; j++)
                bf[j] = *(const short8*)&h1[wc * 64 + j * 16 + rl][k0 + kq * 8];
#pragma unroll
            for (int f = 0; f < 5; f++)
#pragma unroll
                for (int j = 0; j < 4; j++)
                    acc[f][j] = __builtin_amdgcn_mfma_f32_16x16x32_bf16(
                        af[f], bf[j], acc[f][j], 0, 0, 0);
            __syncthreads();
        }
        // epilogue -> global t
#pragma unroll
        for (int f = 0; f < 5; f++) {
            int rowb = wr * 80 + f * 16 + kq * 4;
#pragma unroll
            for (int j = 0; j < 4; j++) {
                int col = ho + wc * 64 + j * 16 + rl;
#pragma unroll
                for (int r = 0; r < 4; r++) {
                    int row = rowb + r;
                    t_out[((size_t)b * NN + row) * HH + col] = f2b(acc[f][j][r]);
                }
            }
        }
    }
}

// ---------- K4: mm2 + pool + head, one block per batch ----------
// h2[i][h] = relu(sum_k t[b][i][k]*W2t[h][k] + b2[h])
// pooled[h] = sum_i h2[i][h] / NN;  out[b] = pooled@Wo + bo + state[b]
__global__ __launch_bounds__(512)
void k_mm2head(const unsigned short* __restrict__ t_in,
               const unsigned short* __restrict__ W2t,
               const float* __restrict__ b2,
               const float* __restrict__ Wo,
               const float* __restrict__ bo,
               const float* __restrict__ state,
               float* __restrict__ out)
{
    constexpr int KS = 40;
    __shared__ __align__(16) unsigned short sT[NN * KS];   // 12.8 KB
    __shared__ __align__(16) unsigned short sW[HH * KS];   // 20.5 KB
    __shared__ float pp2[8][HH];                            // 8 KB (det. slots)
    __shared__ float partials[4][ST];                       // 2 KB
    const int b = blockIdx.x;
    const int tid = threadIdx.x, lane = tid & 63, w = tid >> 6;
    const int wr = w >> 2, wc = w & 3;          // waves 2x4: WM=80, WN=64
    const int rl = lane & 15, kq = lane >> 4;

    f32x4 acc[5][4];
#pragma unroll
    for (int f = 0; f < 5; f++)
#pragma unroll
        for (int j = 0; j < 4; j++) acc[f][j] = f32x4{0.f, 0.f, 0.f, 0.f};

    for (int k0 = 0; k0 < HH; k0 += 32) {
        for (int idx = tid; idx < 640 + 1024; idx += 512) {
            if (idx < 640) {                     // A: t rows (160 x 32-slice)
                int r = idx >> 2, c = (idx & 3) * 8;
                *(short8*)&sT[r * KS + c] =
                    *(const short8*)&t_in[((size_t)b * NN + r) * HH + k0 + c];
            } else {                             // Bt: W2t rows (256 x 32-slice)
                int q = idx - 640;
                int r = q >> 2, c = (q & 3) * 8;
                *(short8*)&sW[r * KS + c] =
                    *(const short8*)&W2t[(size_t)r * HH + k0 + c];
            }
        }
        __syncthreads();
        short8 af[5], bf[4];
#pragma unroll
        for (int f = 0; f < 5; f++)
            af[f] = *(const short8*)&sT[(wr * 80 + f * 16 + rl) * KS + kq * 8];
#pragma unroll
        for (int j = 0; j < 4; j++)
            bf[j] = *(const short8*)&sW[(wc * 64 + j * 16 + rl) * KS + kq * 8];
#pragma unroll
        for (int f = 0; f < 5; f++)
#pragma unroll
            for (int j = 0; j < 4; j++)
                acc[f][j] = __builtin_amdgcn_mfma_f32_16x16x32_bf16(
                    af[f], bf[j], acc[f][j], 0, 0, 0);
        __syncthreads();
    }
    // epilogue: bias+relu, in-lane sum over (f,r), slotted store (deterministic)
    const int slot = wr * 4 + kq;
#pragma unroll
    for (int j = 0; j < 4; j++) {
        int h = wc * 64 + j * 16 + rl;
        float bias = b2[h];
        float s = 0.f;
#pragma unroll
        for (int f = 0; f < 5; f++)
#pragma unroll
            for (int r = 0; r < 4; r++) {
                float v = acc[f][j][r] + bias;
                s += v > 0.f ? v : 0.f;
            }
        pp2[slot][h] = s;
    }
    __syncthreads();
    // head: partial dots over k-quarters
    const int q = tid >> 7, s = tid & 127;
    float part = 0.f;
    for (int k = q * 64; k < q * 64 + 64; k++) {
        float pk = pp2[0][k] + pp2[1][k] + pp2[2][k] + pp2[3][k]
                 + pp2[4][k] + pp2[5][k] + pp2[6][k] + pp2[7][k];
        part += pk * Wo[k * ST + s];
    }
    partials[q][s] = part;
    __syncthreads();
    if (tid < ST) {
        float acc_o = (partials[0][tid] + partials[1][tid] +
                       partials[2][tid] + partials[3][tid]) * (1.0f / NN);
        out[b * ST + tid] = acc_o + bo[tid] + state[b * ST + tid];
    }
}

extern "C" void kernel_launch(void* const* d_in, const int* in_sizes, int n_in,
                              void* d_out, int out_size, void* d_ws, size_t ws_size,
                              hipStream_t stream) {
    const float* state  = (const float*)d_in[0];
    const float* action = (const float*)d_in[1];
    const int*   ei     = (const int*)d_in[2];
    const float* W1     = (const float*)d_in[3];
    const float* b1     = (const float*)d_in[4];
    const float* W2     = (const float*)d_in[5];
    const float* b2     = (const float*)d_in[6];
    const float* Wo     = (const float*)d_in[7];
    const float* bo     = (const float*)d_in[8];
    float* out = (float*)d_out;

    char* ws = (char*)d_ws;
    size_t off = 0;
    auto alloc = [&](size_t bytes) {
        void* p = ws + off;
        off += (bytes + 255) & ~(size_t)255;
        return p;
    };
    float* M    = (float*)alloc(NN * NN * 4);
    float* A    = (float*)alloc(NN * NN * 4);
    float* P    = (float*)alloc(NN * NN * 4);
    unsigned short* Mb  = (unsigned short*)alloc(NN * NN * 2);
    unsigned short* W1t = (unsigned short*)alloc((size_t)HH * NN * 2);
    unsigned short* W2t = (unsigned short*)alloc((size_t)HH * HH * 2);
    unsigned short* t   = (unsigned short*)alloc((size_t)BB * NN * HH * 2);

    k_rows<<<NN, 256, 0, stream>>>(ei, M, A, Mb);
    k_pwt<<<576, 256, 0, stream>>>(M, A, W1, W2, P, W1t, W2t);
    {
        dim3 g(2, BB);   // (h-half, batch) = 256 blocks
        k_l1agg<<<g, 256, 0, stream>>>(P, state, action, W1t, b1, Mb, t);
    }
    k_mm2head<<<BB, 512, 0, stream>>>(t, W2t, b2, Wo, bo, state, out);
}

// Round 5
// 50.268 us; speedup vs baseline: 3.3705x; 1.1623x over previous
//
#include <hip/hip_runtime.h>

#define NN 160      // nodes
#define BB 128      // batch
#define HH 256      // hidden
#define EE 5120     // edges
#define ST 128      // state dim
#define AC 32       // action dim
#define HALF 128    // HH/2

typedef __attribute__((ext_vector_type(8))) short short8;
typedef __attribute__((ext_vector_type(4))) float f32x4;
typedef unsigned short us;

__device__ inline us f2b(float f) {
    unsigned u = __builtin_bit_cast(unsigned, f);
    unsigned r = (u + 0x7FFFu + ((u >> 16) & 1u)) >> 16;
    return (us)r;
}

// ---------- K1: graph rows + P row (int-exact) + weight transposes ----------
// blocks 0..159: row i of M(bf16)+P(f32) via LDS adjacency bitmap
// blocks 160..319: W1t transpose; blocks 320..575: W2t transpose
__global__ __launch_bounds__(256)
void k_pre(const int* __restrict__ ei, const float* __restrict__ W1,
           const float* __restrict__ W2, float* __restrict__ P,
           us* __restrict__ Mb, us* __restrict__ W1t, us* __restrict__ W2t)
{
    const int bx = blockIdx.x, tid = threadIdx.x;
    if (bx < NN) {
        __shared__ int crow[NN];
        __shared__ unsigned abit[NN * NN / 32];   // 800 words = 3.2 KB
        __shared__ float invdeg;
        if (tid < NN) crow[tid] = 0;
        for (int i = tid; i < NN * NN / 32; i += 256) abit[i] = 0;
        __syncthreads();
        for (int e = tid; e < EE; e += 256) {
            int s = ei[e], d = ei[EE + e];
            int p = d * NN + s;
            atomicOr(&abit[p >> 5], 1u << (p & 31));
            if (d == bx) atomicAdd(&crow[s], 1);
        }
        if (tid < NN) {                           // self loops
            int p = tid * NN + tid;
            atomicOr(&abit[p >> 5], 1u << (p & 31));
        }
        __syncthreads();
        if (tid == 0) {
            int dg = 0;
            for (int j = 0; j < NN; j++) dg += crow[j];
            invdeg = 1.0f / (float)(dg < 1 ? 1 : dg);
        }
        __syncthreads();
        if (tid < NN) {
            int s = 0;
            for (int k = 0; k < NN; k++) {        // P[i][t] int-exact
                int p = k * NN + tid;
                if (abit[p >> 5] & (1u << (p & 31))) s += crow[k];
            }
            P[bx * NN + tid]  = (float)s * invdeg;
            Mb[bx * NN + tid] = f2b((float)crow[tid] * invdeg);
        }
    } else if (bx < NN + 160) {                   // W1t: 256x160
        int idx = (bx - NN) * 256 + tid;
        int n = idx / NN, k = idx - n * NN;
        W1t[idx] = f2b(W1[k * HH + n]);
    } else {                                      // W2t: 256x256
        int idx = (bx - NN - 160) * 256 + tid;
        int n = idx >> 8, k = idx & 255;
        W2t[idx] = f2b(W2[k * HH + n]);
    }
}

// ---------- K2: whole per-batch pipeline, one block per batch ----------
// hh-loop: GEMM1 h1[hh][i] (LDS) -> GEMM2 t[i][ho+hh] (LDS)
// then GEMM3 (mm2) from LDS t -> pool -> head -> out
__global__ __launch_bounds__(512)
void k_mega(const float* __restrict__ P, const float* __restrict__ state,
            const float* __restrict__ action, const us* __restrict__ W1t,
            const float* __restrict__ b1, const us* __restrict__ Mb,
            const us* __restrict__ W2t, const float* __restrict__ b2,
            const float* __restrict__ Wo, const float* __restrict__ bo,
            float* __restrict__ out)
{
    constexpr int KS = 40;    // staging K-stride (shorts)
    constexpr int H1S = 168;  // h1 row stride
    constexpr int TS = 264;   // t row stride (256+8; 2-way bank alias = free)
    __shared__ float xb[NN];                          //   640 B
    __shared__ __align__(16) us t_lds[NN][TS];        // 84480 B
    __shared__ __align__(16) us h1[HALF][H1S];        // 43008 B
    __shared__ __align__(16) us stg[(NN + HALF) * KS];// 23040 B
    __shared__ float pp2[8][HH];                      //  8192 B
    __shared__ float partials[4][ST];                 //  2048 B  => 161408 B
    us* sY  = stg;             // [NN][KS]   GEMM1 Bt
    us* sW  = stg + NN * KS;   // [HALF][KS] GEMM1 A
    us* sM  = stg;             // [NN][KS]   GEMM2 A
    us* sW2 = stg;             // [HH][KS]   GEMM3 Bt (10240 <= 11520 shorts)

    const int b = blockIdx.x;
    const int tid = threadIdx.x, lane = tid & 63, w = tid >> 6;  // 8 waves
    const int rl = lane & 15, kq = lane >> 4;

    if (tid < NN) xb[tid] = (tid < ST) ? state[b * ST + tid]
                                       : action[b * AC + (tid - ST)];
    __syncthreads();

    for (int hh = 0; hh < 2; hh++) {
        const int ho = hh * HALF;
        // ---- GEMM1: M=128(h-half), N=160(i), K=160(j). waves 4x2: WM=32,WN=80
        {
            const int wr = w >> 1, wc = w & 1;
            f32x4 acc[2][5];
#pragma unroll
            for (int f = 0; f < 2; f++)
#pragma unroll
                for (int j = 0; j < 5; j++) acc[f][j] = f32x4{0.f, 0.f, 0.f, 0.f};

            for (int k0 = 0; k0 < NN; k0 += 32) {
                for (int idx = tid; idx < 512 + 640; idx += 512) {
                    if (idx < 512) {              // A: W1t half rows
                        int r = idx >> 2, c = (idx & 3) * 8;
                        *(short8*)&sW[r * KS + c] =
                            *(const short8*)&W1t[(size_t)(ho + r) * NN + k0 + c];
                    } else {                      // Bt: Y = bf16(P*x) on the fly
                        int q = idx - 512;
                        int r = q >> 2, c = (q & 3) * 8;
                        const f32x4* p4 = (const f32x4*)&P[r * NN + k0 + c];
                        f32x4 p0 = p4[0], p1 = p4[1];
                        short8 y;
#pragma unroll
                        for (int u = 0; u < 4; u++) {
                            y[u]     = (short)f2b(p0[u] * xb[k0 + c + u]);
                            y[u + 4] = (short)f2b(p1[u] * xb[k0 + c + 4 + u]);
                        }
                        *(short8*)&sY[r * KS + c] = y;
                    }
                }
                __syncthreads();
                short8 af[2], bf[5];
#pragma unroll
                for (int f = 0; f < 2; f++)
                    af[f] = *(const short8*)&sW[(wr * 32 + f * 16 + rl) * KS + kq * 8];
#pragma unroll
                for (int j = 0; j < 5; j++)
                    bf[j] = *(const short8*)&sY[(wc * 80 + j * 16 + rl) * KS + kq * 8];
#pragma unroll
                for (int f = 0; f < 2; f++)
#pragma unroll
                    for (int j = 0; j < 5; j++)
                        acc[f][j] = __builtin_amdgcn_mfma_f32_16x16x32_bf16(
                            af[f], bf[j], acc[f][j], 0, 0, 0);
                __syncthreads();
            }
            // epilogue -> h1 (bias+relu). row(h)=wr*32+f*16+kq*4+r, col(i)=wc*80+j*16+rl
#pragma unroll
            for (int f = 0; f < 2; f++) {
                int rowb = wr * 32 + f * 16 + kq * 4;
#pragma unroll
                for (int j = 0; j < 5; j++) {
                    int col = wc * 80 + j * 16 + rl;
#pragma unroll
                    for (int r = 0; r < 4; r++) {
                        int row = rowb + r;
                        float v = acc[f][j][r] + b1[ho + row];
                        h1[row][col] = f2b(v > 0.f ? v : 0.f);
                    }
                }
            }
        }
        __syncthreads();
        // ---- GEMM2: M=160(i), N=128(h-half), K=160(k). waves 2x4: WM=80,WN=32
        {
            const int wr = w >> 2, wc = w & 3;
            f32x4 acc[5][2];
#pragma unroll
            for (int f = 0; f < 5; f++)
#pragma unroll
                for (int j = 0; j < 2; j++) acc[f][j] = f32x4{0.f, 0.f, 0.f, 0.f};

            for (int k0 = 0; k0 < NN; k0 += 32) {
                for (int idx = tid; idx < 640; idx += 512) {
                    int r = idx >> 2, c = (idx & 3) * 8;
                    *(short8*)&sM[r * KS + c] =
                        *(const short8*)&Mb[(size_t)r * NN + k0 + c];
                }
                __syncthreads();
                short8 af[5], bf[2];
#pragma unroll
                for (int f = 0; f < 5; f++)
                    af[f] = *(const short8*)&sM[(wr * 80 + f * 16 + rl) * KS + kq * 8];
#pragma unroll
                for (int j = 0; j < 2; j++)
                    bf[j] = *(const short8*)&h1[wc * 32 + j * 16 + rl][k0 + kq * 8];
#pragma unroll
                for (int f = 0; f < 5; f++)
#pragma unroll
                    for (int j = 0; j < 2; j++)
                        acc[f][j] = __builtin_amdgcn_mfma_f32_16x16x32_bf16(
                            af[f], bf[j], acc[f][j], 0, 0, 0);
                __syncthreads();
            }
            // epilogue -> t_lds. row(i)=wr*80+f*16+kq*4+r, col=ho+wc*32+j*16+rl
#pragma unroll
            for (int f = 0; f < 5; f++) {
                int rowb = wr * 80 + f * 16 + kq * 4;
#pragma unroll
                for (int j = 0; j < 2; j++) {
                    int col = ho + wc * 32 + j * 16 + rl;
#pragma unroll
                    for (int r = 0; r < 4; r++)
                        t_lds[rowb + r][col] = f2b(acc[f][j][r]);
                }
            }
        }
        __syncthreads();
    }

    // ---- GEMM3: M=160(i), N=256(h), K=256. waves 2x4: WM=80, WN=64. A from LDS t
    {
        const int wr = w >> 2, wc = w & 3;
        f32x4 acc[5][4];
#pragma unroll
        for (int f = 0; f < 5; f++)
#pragma unroll
            for (int j = 0; j < 4; j++) acc[f][j] = f32x4{0.f, 0.f, 0.f, 0.f};

        for (int k0 = 0; k0 < HH; k0 += 32) {
            for (int idx = tid; idx < 1024; idx += 512) {
                int r = idx >> 2, c = (idx & 3) * 8;
                *(short8*)&sW2[r * KS + c] =
                    *(const short8*)&W2t[(size_t)r * HH + k0 + c];
            }
            __syncthreads();
            short8 af[5], bf[4];
#pragma unroll
            for (int f = 0; f < 5; f++)
                af[f] = *(const short8*)&t_lds[wr * 80 + f * 16 + rl][k0 + kq * 8];
#pragma unroll
            for (int j = 0; j < 4; j++)
                bf[j] = *(const short8*)&sW2[(wc * 64 + j * 16 + rl) * KS + kq * 8];
#pragma unroll
            for (int f = 0; f < 5; f++)
#pragma unroll
                for (int j = 0; j < 4; j++)
                    acc[f][j] = __builtin_amdgcn_mfma_f32_16x16x32_bf16(
                        af[f], bf[j], acc[f][j], 0, 0, 0);
            __syncthreads();
        }
        // epilogue: bias+relu, in-lane sum over (f,r) rows, slotted store
        const int slot = wr * 4 + kq;
#pragma unroll
        for (int j = 0; j < 4; j++) {
            int h = wc * 64 + j * 16 + rl;
            float bias = b2[h];
            float s = 0.f;
#pragma unroll
            for (int f = 0; f < 5; f++)
#pragma unroll
                for (int r = 0; r < 4; r++) {
                    float v = acc[f][j][r] + bias;
                    s += v > 0.f ? v : 0.f;
                }
            pp2[slot][h] = s;
        }
    }
    __syncthreads();
    // head: out[b] = (pool/NN)@Wo + bo + state[b]
    {
        const int q = tid >> 7, s = tid & 127;
        float part = 0.f;
        for (int k = q * 64; k < q * 64 + 64; k++) {
            float pk = pp2[0][k] + pp2[1][k] + pp2[2][k] + pp2[3][k]
                     + pp2[4][k] + pp2[5][k] + pp2[6][k] + pp2[7][k];
            part += pk * Wo[k * ST + s];
        }
        partials[q][s] = part;
        __syncthreads();
        if (tid < ST) {
            float acc_o = (partials[0][tid] + partials[1][tid] +
                           partials[2][tid] + partials[3][tid]) * (1.0f / NN);
            out[b * ST + tid] = acc_o + bo[tid] + state[b * ST + tid];
        }
    }
}

extern "C" void kernel_launch(void* const* d_in, const int* in_sizes, int n_in,
                              void* d_out, int out_size, void* d_ws, size_t ws_size,
                              hipStream_t stream) {
    const float* state  = (const float*)d_in[0];
    const float* action = (const float*)d_in[1];
    const int*   ei     = (const int*)d_in[2];
    const float* W1     = (const float*)d_in[3];
    const float* b1     = (const float*)d_in[4];
    const float* W2     = (const float*)d_in[5];
    const float* b2     = (const float*)d_in[6];
    const float* Wo     = (const float*)d_in[7];
    const float* bo     = (const float*)d_in[8];
    float* out = (float*)d_out;

    char* ws = (char*)d_ws;
    size_t off = 0;
    auto alloc = [&](size_t bytes) {
        void* p = ws + off;
        off += (bytes + 255) & ~(size_t)255;
        return p;
    };
    float* P   = (float*)alloc(NN * NN * 4);
    us* Mb  = (us*)alloc(NN * NN * 2);
    us* W1t = (us*)alloc((size_t)HH * NN * 2);
    us* W2t = (us*)alloc((size_t)HH * HH * 2);

    k_pre<<<NN + 160 + 256, 256, 0, stream>>>(ei, W1, W2, P, Mb, W1t, W2t);
    k_mega<<<BB, 512, 0, stream>>>(P, state, action, W1t, b1, Mb, W2t, b2,
                                   Wo, bo, out);
}